// Round 12
// baseline (209.866 us; speedup 1.0000x reference)
//
#include <hip/hip_runtime.h>
#include <hip/hip_bf16.h>

#define NB 4
#define NS 2048
#define ND 768
#define NH 12
#define NDH 64
#define NM (NB * NS)  // 8192

// fold 1/sqrt(64) * log2(e) into Q so softmax = exp2(s); mask pre-scaled
#define QSCALE 0.1803368867f
#define MSCALE (-1.442695041e9f)

typedef __attribute__((ext_vector_type(8))) short short8;    // 8 x bf16
typedef __attribute__((ext_vector_type(4))) float f32x4;
typedef __attribute__((ext_vector_type(16))) float f32x16;

__device__ __forceinline__ void async_ld16(const void* g, void* l) {
  __builtin_amdgcn_global_load_lds(
      (const __attribute__((address_space(1))) void*)g,
      (__attribute__((address_space(3))) void*)l, 16, 0, 0);
}

// plain scalar packing — compiler pairs these into v_cvt_pk_bf16_f32
__device__ __forceinline__ unsigned pack_bf16(float a, float b) {
  return ((unsigned)__bfloat16_as_ushort(__float2bfloat16(b)) << 16) |
         (unsigned)__bfloat16_as_ushort(__float2bfloat16(a));
}

// VALU cross-half exchange
__device__ __forceinline__ void permlane_swap(unsigned& a, unsigned& b) {
  asm("v_permlane32_swap_b32 %0, %1" : "+v"(a), "+v"(b));
}

// raw v_exp_f32: exp2 with flush-to-zero for large-negative (exact for mask)
__device__ __forceinline__ float fast_exp2(float x) {
  float r;
  asm("v_exp_f32 %0, %1" : "=v"(r) : "v"(x));
  return r;
}

// ---------------- f32 -> bf16 convert (vectorized, 8/thread) --------------
__global__ __launch_bounds__(256) void convert_bf16_kernel(
    const float* __restrict__ in, __hip_bfloat16* __restrict__ out, int n8) {
  const int i = blockIdx.x * 256 + threadIdx.x;
  if (i >= n8) return;
  const float4 a = ((const float4*)in)[i * 2];
  const float4 b = ((const float4*)in)[i * 2 + 1];
  short8 v;
  __hip_bfloat16* p = (__hip_bfloat16*)&v;
  p[0] = __float2bfloat16(a.x); p[1] = __float2bfloat16(a.y);
  p[2] = __float2bfloat16(a.z); p[3] = __float2bfloat16(a.w);
  p[4] = __float2bfloat16(b.x); p[5] = __float2bfloat16(b.y);
  p[6] = __float2bfloat16(b.z); p[7] = __float2bfloat16(b.w);
  ((short8*)out)[i] = v;
}

// ------- mask precompute: crow-permuted + scaled + per-(b,tile) bitmap ----
__global__ __launch_bounds__(256) void mask_perm_kernel(
    const float* __restrict__ mask, float* __restrict__ mperm_g,
    unsigned* __restrict__ mbits) {
  const int idx = blockIdx.x * 256 + threadIdx.x;  // 0..8191
  const int b = idx >> 11;
  const int sb = idx & 2047;
  const int tile = sb >> 6, slot = sb & 63;
  const int g = slot >> 5, hh = (slot >> 4) & 1, r = slot & 15;
  const int key = tile * 64 + g * 32 + 4 * hh + (r & 3) + 8 * (r >> 2);
  const float v = mask[b * NS + key];
  mperm_g[idx] = v * MSCALE;
  if (v != 0.f) atomicOr(&mbits[b], 1u << tile);
}

// ------- weight transpose+convert: W[K][N] f32 -> Wt[N][K] bf16 -----------
__global__ __launch_bounds__(256) void transpose_w_kernel(
    const float* __restrict__ w0, const float* __restrict__ w1,
    const float* __restrict__ w2, const float* __restrict__ w3,
    __hip_bfloat16* __restrict__ WtAll) {
  __shared__ __hip_bfloat16 tile[64][66];
  const float* src = blockIdx.z == 0 ? w0 : blockIdx.z == 1 ? w1
                   : blockIdx.z == 2 ? w2 : w3;
  __hip_bfloat16* dst = WtAll + (size_t)blockIdx.z * ND * ND;
  const int kk0 = blockIdx.y * 64, nn0 = blockIdx.x * 64;
  const int t = threadIdx.x;
#pragma unroll
  for (int p = 0; p < 4; ++p) {
    const int idx = p * 256 + t;
    const int k = idx >> 4;
    const int c = (idx & 15) * 4;
    const float4 v = *(const float4*)(src + (size_t)(kk0 + k) * ND + nn0 + c);
    __hip_bfloat162* tp = (__hip_bfloat162*)&tile[k][c];
    tp[0] = __hip_bfloat162{__float2bfloat16(v.x), __float2bfloat16(v.y)};
    tp[1] = __hip_bfloat162{__float2bfloat16(v.z), __float2bfloat16(v.w)};
  }
  __syncthreads();
#pragma unroll
  for (int p = 0; p < 2; ++p) {
    const int idx = p * 256 + t;
    const int n = idx >> 3;
    const int kb = (idx & 7) * 8;
    short8 v;
    __hip_bfloat16* pv = (__hip_bfloat16*)&v;
#pragma unroll
    for (int j = 0; j < 8; ++j) pv[j] = tile[kb + j][n];
    *(short8*)(dst + (size_t)(nn0 + n) * ND + kk0 + kb) = v;
  }
}

// ------- fused QKV GEMM: 128x128 tile, BK=32, XCD-grouped blocks ----------
__global__ __launch_bounds__(256) void qkv_gemm_kernel(
    const __hip_bfloat16* __restrict__ A,
    const __hip_bfloat16* __restrict__ Bt,
    const float* __restrict__ bq, const float* __restrict__ bk,
    const float* __restrict__ bv,
    __hip_bfloat16* __restrict__ Qw, __hip_bfloat16* __restrict__ Kw,
    __hip_bfloat16* __restrict__ Vt) {
  __shared__ __hip_bfloat16 As[128 * 32];  // [row][k] 8KB
  __shared__ __hip_bfloat16 Bs[128 * 32];  // [col][k] 8KB
  const int K = ND;
  const int tid = threadIdx.x;
  const int w = tid >> 6, l = tid & 63;
  const int lk = l & 15, lt = l >> 4;
  // bijective XCD grouping: 1152 blocks = 8 * 144
  const int p = blockIdx.x + 18 * blockIdx.y;
  const int swzb = (p & 7) * 144 + (p >> 3);
  const int m0 = (swzb / 18) * 128, n0 = (swzb % 18) * 128;
  const int wr = w >> 1, wc = w & 1;

  f32x4 acc[4][4] = {};

  const int arow = w * 32 + (l >> 2);   // +16 for second load
  const int acol = (l & 3) * 8;
  const __hip_bfloat16* aptr = A + (size_t)(m0 + arow) * K + acol;
  const __hip_bfloat16* bptr = Bt + (size_t)(n0 + arow) * K + acol;
  __hip_bfloat16* asb = As + w * 1024;
  __hip_bfloat16* bsb = Bs + w * 1024;

  for (int k0 = 0; k0 < K; k0 += 32) {
    __syncthreads();
    async_ld16(aptr + k0, asb);
    async_ld16(aptr + (size_t)16 * K + k0, asb + 512);
    async_ld16(bptr + k0, bsb);
    async_ld16(bptr + (size_t)16 * K + k0, bsb + 512);
    __syncthreads();

    short8 af[4], bf[4];
#pragma unroll
    for (int m = 0; m < 4; ++m)
      af[m] = *(const short8*)(As + (wr * 64 + m * 16 + lk) * 32 + lt * 8);
#pragma unroll
    for (int n = 0; n < 4; ++n)
      bf[n] = *(const short8*)(Bs + (wc * 64 + n * 16 + lk) * 32 + lt * 8);
#pragma unroll
    for (int m = 0; m < 4; ++m)
#pragma unroll
      for (int n = 0; n < 4; ++n)
        acc[m][n] =
            __builtin_amdgcn_mfma_f32_16x16x32_bf16(af[m], bf[n], acc[m][n], 0, 0, 0);
  }

  const int mi = n0 / ND;          // 0=Q, 1=K, 2=V (768/128=6: no straddle)
  const int nbase = n0 - mi * ND;
  const float* bp = mi == 0 ? bq : mi == 1 ? bk : bv;
  const float oscale = (mi == 0) ? QSCALE : 1.f;

#pragma unroll
  for (int n = 0; n < 4; ++n) {
    const int col = nbase + wc * 64 + n * 16 + lk;
    const float bb = bp[col];
#pragma unroll
    for (int m = 0; m < 4; ++m) {
      const int row = m0 + wr * 64 + m * 16 + lt * 4;
#pragma unroll
      for (int r = 0; r < 4; ++r) {
        const float v = (acc[m][n][r] + bb) * oscale;
        if (mi < 2) {
          (mi ? Kw : Qw)[(size_t)(row + r) * ND + col] = __float2bfloat16(v);
        } else {
          const int mrow = row + r;
          const int bidx = mrow >> 11, s = mrow & 2047;
          const int hh = col >> 6, dh = col & 63;
          Vt[(((size_t)bidx * NH + hh) * NDH + dh) * NS + s] = __float2bfloat16(v);
        }
      }
    }
  }
}

// ---------------- MFMA-32x32 flash attention, QBLK=64 per wave ------------
// 2 waves x 64 q-rows = 128 q per block (768 blocks, 3/CU). K/V fragment
// reads are shared across the wave's two q-groups -> LDS reads per q halve.
// Two key-halves per tile cap live S registers. MFMA denominator (ones).
__global__ __launch_bounds__(128) void mha_mfma32_kernel(
    const __hip_bfloat16* __restrict__ Qb, const __hip_bfloat16* __restrict__ Kb,
    const __hip_bfloat16* __restrict__ Vt, const float* __restrict__ mperm_g,
    const unsigned* __restrict__ maskbits, __hip_bfloat16* __restrict__ ctx) {
  // [0,16384): K bufs (2x8KB) | [16384,32768): V bufs; epilogue reuses all
  __shared__ __align__(16) char smem[32768];
  char* KsB = smem;
  char* VsB = smem + 16384;

  // bijective XCD swizzle: physical p -> logical (p&7)*96 + (p>>3)
  const int p = blockIdx.x + 16 * (blockIdx.y + 12 * blockIdx.z);
  const int logical = (p & 7) * 96 + (p >> 3);
  const int lx = logical & 15;         // q-tile (128 q)
  const int rest = logical >> 4;       // 0..47
  const int h = rest % 12;
  const int b = rest / 12;

  const int tid = threadIdx.x;
  const int w = tid >> 6, l = tid & 63;   // w in {0,1}
  const int l31 = l & 31, hi = l >> 5;
  const int q0 = lx * 128 + w * 64;
  const unsigned mbitsb = maskbits[b];   // wave-uniform

  // Q fragments for the wave's two q-groups (qA: q0+l31, qB: q0+32+l31)
  const __hip_bfloat16* qpA = Qb + ((size_t)b * NS + q0 + l31) * ND + h * NDH;
  const __hip_bfloat16* qpB = qpA + 32 * ND;
  short8 qfA[4], qfB[4];
#pragma unroll
  for (int ks = 0; ks < 4; ++ks) {
    qfA[ks] = *(const short8*)(qpA + ks * 16 + hi * 8);
    qfB[ks] = *(const short8*)(qpB + ks * 16 + hi * 8);
  }

  const short ONEB = 0x3F80;
  const short8 ones = {ONEB, ONEB, ONEB, ONEB, ONEB, ONEB, ONEB, ONEB};

  f32x16 cA0 = {}, cA1 = {}, cB0 = {}, cB1 = {}, lA = {}, lB = {};
  const f32x16 z16 = {};

  // staging: wave w stages K rows w*32..w*32+31 and V rows (dh) likewise,
  // 4 DMAs each; source col pre-swizzled so LDS stays linear.
  const int srow = w * 32 + (l >> 3);
  const int colswz = ((l & 7) ^ (l >> 3)) * 8;   // (slot ^ row&7)*8
  const __hip_bfloat16* kg =
      Kb + ((size_t)b * NS + srow) * ND + h * NDH + colswz;
  const __hip_bfloat16* vg =
      Vt + (((size_t)b * NH + h) * NDH + srow) * NS + colswz;
  const float* mg = mperm_g + (size_t)b * NS;

  // 8 async loads per wave per stage
#define STAGE(buf, t)                                                        \
  {                                                                          \
    char* kd = KsB + (buf) * 8192 + w * 4096;                                \
    char* vd = VsB + (buf) * 8192 + w * 4096;                                \
    const size_t koff = (size_t)(t) * 64 * ND;                               \
    async_ld16(kg + koff, kd);                                               \
    async_ld16(kg + koff + (size_t)8 * ND, kd + 1024);                       \
    async_ld16(kg + koff + (size_t)16 * ND, kd + 2048);                      \
    async_ld16(kg + koff + (size_t)24 * ND, kd + 3072);                      \
    async_ld16(vg + (t) * 64, vd);                                           \
    async_ld16(vg + (t) * 64 + 8 * NS, vd + 1024);                           \
    async_ld16(vg + (t) * 64 + 16 * NS, vd + 2048);                          \
    async_ld16(vg + (t) * 64 + 24 * NS, vd + 3072);                          \
  }

  const int swz = (l31 & 7) << 4;

  auto compute_tile = [&](int t, int cur2) {
    const int bufo = cur2 * 8192;
    const float* mgt = mg + t * 64 + hi * 16;
    const bool hasmask = (mbitsb >> t) & 1;

    // ============ keysLo: K rows l31, P slots 0,1 ============
    {
      f32x16 sA, sB;
      const int ro = bufo + (l31 << 7);
#pragma unroll
      for (int ks = 0; ks < 4; ++ks) {
        const short8 kf =
            *(const short8*)(KsB + ro + (((ks << 5) | (hi << 4)) ^ swz));
        if (ks == 0) {
          sA = __builtin_amdgcn_mfma_f32_32x32x16_bf16(kf, qfA[0], z16, 0, 0, 0);
          sB = __builtin_amdgcn_mfma_f32_32x32x16_bf16(kf, qfB[0], z16, 0, 0, 0);
        } else {
          sA = __builtin_amdgcn_mfma_f32_32x32x16_bf16(kf, qfA[ks], sA, 0, 0, 0);
          sB = __builtin_amdgcn_mfma_f32_32x32x16_bf16(kf, qfB[ks], sB, 0, 0, 0);
        }
      }
      if (hasmask) {
#pragma unroll
        for (int r = 0; r < 16; ++r) {
          sA[r] += mgt[r];
          sB[r] += mgt[r];
        }
      }
#pragma unroll
      for (int r = 0; r < 16; ++r) sA[r] = fast_exp2(sA[r]);
#pragma unroll
      for (int r = 0; r < 16; ++r) sB[r] = fast_exp2(sB[r]);

#pragma unroll
      for (int ss = 0; ss < 2; ++ss) {
        const int r0 = ss * 8;
        unsigned a0 = pack_bf16(sA[r0 + 0], sA[r0 + 1]);
        unsigned a1 = pack_bf16(sA[r0 + 2], sA[r0 + 3]);
        unsigned a2 = pack_bf16(sA[r0 + 4], sA[r0 + 5]);
        unsigned a3 = pack_bf16(sA[r0 + 6], sA[r0 + 7]);
        permlane_swap(a0, a2);
        permlane_swap(a1, a3);
        union { unsigned u[4]; short8 v; } pfA = {{a0, a1, a2, a3}};
        unsigned b0 = pack_bf16(sB[r0 + 0], sB[r0 + 1]);
        unsigned b1 = pack_bf16(sB[r0 + 2], sB[r0 + 3]);
        unsigned b2 = pack_bf16(sB[r0 + 4], sB[r0 + 5]);
        unsigned b3 = pack_bf16(sB[r0 + 6], sB[r0 + 7]);
        permlane_swap(b0, b2);
        permlane_swap(b1, b3);
        union { unsigned u[4]; short8 v; } pfB = {{b0, b1, b2, b3}};
        const int off = bufo + (((ss << 5) | (hi << 4)) ^ swz);
        const short8 vf0 = *(const short8*)(VsB + off + (l31 << 7));
        const short8 vf1 = *(const short8*)(VsB + off + ((32 + l31) << 7));
        cA0 = __builtin_amdgcn_mfma_f32_32x32x16_bf16(vf0, pfA.v, cA0, 0, 0, 0);
        cA1 = __builtin_amdgcn_mfma_f32_32x32x16_bf16(vf1, pfA.v, cA1, 0, 0, 0);
        cB0 = __builtin_amdgcn_mfma_f32_32x32x16_bf16(vf0, pfB.v, cB0, 0, 0, 0);
        cB1 = __builtin_amdgcn_mfma_f32_32x32x16_bf16(vf1, pfB.v, cB1, 0, 0, 0);
        lA = __builtin_amdgcn_mfma_f32_32x32x16_bf16(ones, pfA.v, lA, 0, 0, 0);
        lB = __builtin_amdgcn_mfma_f32_32x32x16_bf16(ones, pfB.v, lB, 0, 0, 0);
      }
    }

    // ============ keysHi: K rows 32+l31, P slots 2,3 ============
    {
      f32x16 sA, sB;
      const int ro = bufo + ((32 + l31) << 7);
#pragma unroll
      for (int ks = 0; ks < 4; ++ks) {
        const short8 kf =
            *(const short8*)(KsB + ro + (((ks << 5) | (hi << 4)) ^ swz));
        if (ks == 0) {
          sA = __builtin_amdgcn_mfma_f32_32x32x16_bf16(kf, qfA[0], z16, 0, 0, 0);
          sB = __builtin_amdgcn_mfma_f32_32x32x16_bf16(kf, qfB[0], z16, 0, 0, 0);
        } else {
          sA = __builtin_amdgcn_mfma_f32_32x32x16_bf16(kf, qfA[ks], sA, 0, 0, 0);
          sB = __builtin_amdgcn_mfma_f32_32x32x16_bf16(kf, qfB[ks], sB, 0, 0, 0);
        }
      }
      if (hasmask) {
#pragma unroll
        for (int r = 0; r < 16; ++r) {
          sA[r] += mgt[32 + r];
          sB[r] += mgt[32 + r];
        }
      }
#pragma unroll
      for (int r = 0; r < 16; ++r) sA[r] = fast_exp2(sA[r]);
#pragma unroll
      for (int r = 0; r < 16; ++r) sB[r] = fast_exp2(sB[r]);

#pragma unroll
      for (int ss = 2; ss < 4; ++ss) {
        const int r0 = (ss - 2) * 8;
        unsigned a0 = pack_bf16(sA[r0 + 0], sA[r0 + 1]);
        unsigned a1 = pack_bf16(sA[r0 + 2], sA[r0 + 3]);
        unsigned a2 = pack_bf16(sA[r0 + 4], sA[r0 + 5]);
        unsigned a3 = pack_bf16(sA[r0 + 6], sA[r0 + 7]);
        permlane_swap(a0, a2);
        permlane_swap(a1, a3);
        union { unsigned u[4]; short8 v; } pfA = {{a0, a1, a2, a3}};
        unsigned b0 = pack_bf16(sB[r0 + 0], sB[r0 + 1]);
        unsigned b1 = pack_bf16(sB[r0 + 2], sB[r0 + 3]);
        unsigned b2 = pack_bf16(sB[r0 + 4], sB[r0 + 5]);
        unsigned b3 = pack_bf16(sB[r0 + 6], sB[r0 + 7]);
        permlane_swap(b0, b2);
        permlane_swap(b1, b3);
        union { unsigned u[4]; short8 v; } pfB = {{b0, b1, b2, b3}};
        const int off = bufo + (((ss << 5) | (hi << 4)) ^ swz);
        const short8 vf0 = *(const short8*)(VsB + off + (l31 << 7));
        const short8 vf1 = *(const short8*)(VsB + off + ((32 + l31) << 7));
        cA0 = __builtin_amdgcn_mfma_f32_32x32x16_bf16(vf0, pfA.v, cA0, 0, 0, 0);
        cA1 = __builtin_amdgcn_mfma_f32_32x32x16_bf16(vf1, pfA.v, cA1, 0, 0, 0);
        cB0 = __builtin_amdgcn_mfma_f32_32x32x16_bf16(vf0, pfB.v, cB0, 0, 0, 0);
        cB1 = __builtin_amdgcn_mfma_f32_32x32x16_bf16(vf1, pfB.v, cB1, 0, 0, 0);
        lA = __builtin_amdgcn_mfma_f32_32x32x16_bf16(ones, pfA.v, lA, 0, 0, 0);
        lB = __builtin_amdgcn_mfma_f32_32x32x16_bf16(ones, pfB.v, lB, 0, 0, 0);
      }
    }
  };

  STAGE(0, 0);
  for (int t = 0; t < 32; ++t) {
    // tile t's 8 loads done; both waves synced -> buf (t+1)&1 free
    asm volatile("s_waitcnt vmcnt(0) lgkmcnt(0)" ::: "memory");
    __builtin_amdgcn_s_barrier();
    if (t + 1 < 32) STAGE((t + 1) & 1, t + 1);
    compute_tile(t, t & 1);
  }

  const float invA = 1.f / lA[0];
  const float invB = 1.f / lB[0];

  // ---- epilogue: LDS bounce [64][76] per wave -> coalesced stores ----
  __syncthreads();
  __hip_bfloat16* cb = (__hip_bfloat16*)(smem + w * 9728);  // 64*76*2 B
#pragma unroll
  for (int mg2 = 0; mg2 < 2; ++mg2) {
    const f32x16& ca = mg2 ? cA1 : cA0;
    const f32x16& cbv = mg2 ? cB1 : cB0;
#pragma unroll
    for (int rr = 0; rr < 4; ++rr) {
      const unsigned a0 = pack_bf16(ca[rr * 4 + 0] * invA, ca[rr * 4 + 1] * invA);
      const unsigned a1 = pack_bf16(ca[rr * 4 + 2] * invA, ca[rr * 4 + 3] * invA);
      *(uint2*)(cb + l31 * 76 + mg2 * 32 + 4 * hi + 8 * rr) = uint2{a0, a1};
      const unsigned b0 = pack_bf16(cbv[rr * 4 + 0] * invB, cbv[rr * 4 + 1] * invB);
      const unsigned b1 = pack_bf16(cbv[rr * 4 + 2] * invB, cbv[rr * 4 + 3] * invB);
      *(uint2*)(cb + (32 + l31) * 76 + mg2 * 32 + 4 * hi + 8 * rr) = uint2{b0, b1};
    }
  }
  __syncthreads();
#pragma unroll
  for (int i = 0; i < 8; ++i) {
    const int row = i * 8 + (l >> 3);
    const __hip_bfloat16* crd = cb + row * 76 + (l & 7) * 8;
    const uint2 a = *(const uint2*)(crd);
    const uint2 b2 = *(const uint2*)(crd + 4);
    __hip_bfloat16* gout =
        ctx + ((size_t)b * NS + q0 + row) * ND + h * NDH + (l & 7) * 8;
    *(uint4*)(gout) = uint4{a.x, a.y, b2.x, b2.y};
  }
#undef STAGE
}

// ---------------- MFMA GEMM (output proj): 128x64, f32 out ----------------
__global__ __launch_bounds__(256) void gemm_bt_mfma_kernel(
    const __hip_bfloat16* __restrict__ A, const __hip_bfloat16* __restrict__ Bt,
    const float* __restrict__ bias, float* __restrict__ Cout,
    int M, int N, int K) {
  __shared__ __hip_bfloat16 As[128 * 32];
  __shared__ __hip_bfloat16 Bs[64 * 32];
  const int tid = threadIdx.x;
  const int w = tid >> 6, l = tid & 63;
  const int lk = l & 15, lt = l >> 4;
  // bijective XCD grouping: 768 blocks = 8 * 96
  const int p = blockIdx.x + 12 * blockIdx.y;
  const int swzb = (p & 7) * 96 + (p >> 3);
  const int m0 = (swzb / 12) * 128, n0 = (swzb % 12) * 64;
  const int wr = w >> 1, wc = w & 1;

  f32x4 acc[4][2] = {};

  const int arow = w * 32 + (l >> 2);
  const int acol = (l & 3) * 8;
  const __hip_bfloat16* aptr = A + (size_t)(m0 + arow) * K + acol;
  const int brow = w * 16 + (l >> 2);
  const __hip_bfloat16* bptr = Bt + (size_t)(n0 + brow) * K + acol;
  __hip_bfloat16* asb = As + w * 1024;
  __hip_bfloat16* bsb = Bs + w * 512;

  for (int k0 = 0; k0 < K; k0 += 32) {
    __syncthreads();
    async_ld16(aptr + k0, asb);
    async_ld16(aptr + (size_t)16 * K + k0, asb + 512);
    async_ld16(bptr + k0, bsb);
    __syncthreads();

    short8 af[4], bf[2];
#pragma unroll
    for (int m = 0; m < 4; ++m)
      af[m] = *(const short8*)(As + (wr * 64 + m * 16 + lk) * 32 + lt * 8);
#pragma unroll
    for (int n = 0; n < 2; ++n)
      bf[n] = *(const short8*)(Bs + (wc * 32 + n * 16 + lk) * 32 + lt * 8);
#pragma unroll
    for (int m = 0; m < 4; ++m)
#pragma unroll
      for (int n = 0; n < 2; ++n)
        acc[m][n] =
            __builtin_amdgcn_mfma_f32_16x16x32_bf16(af[m], bf[n], acc[m][n], 0, 0, 0);
  }

#pragma unroll
  for (int n = 0; n < 2; ++n) {
    const int col = n0 + wc * 32 + n * 16 + lk;
    const float bb = bias[col];
#pragma unroll
    for (int m = 0; m < 4; ++m) {
      const int row = m0 + wr * 64 + m * 16 + lt * 4;
#pragma unroll
      for (int r = 0; r < 4; ++r)
        Cout[(size_t)(row + r) * N + col] = acc[m][n][r] + bb;
    }
  }
}

extern "C" void kernel_launch(void* const* d_in, const int* in_sizes, int n_in,
                              void* d_out, int out_size, void* d_ws, size_t ws_size,
                              hipStream_t stream) {
  const float* x    = (const float*)d_in[0];
  const float* mask = (const float*)d_in[1];
  const float* wq   = (const float*)d_in[2];
  const float* bq   = (const float*)d_in[3];
  const float* wk   = (const float*)d_in[4];
  const float* bk   = (const float*)d_in[5];
  const float* wv   = (const float*)d_in[6];
  const float* bv   = (const float*)d_in[7];
  const float* wo   = (const float*)d_in[8];
  const float* bo   = (const float*)d_in[9];
  float* out = (float*)d_out;

  const size_t mat = (size_t)NM * ND;
  const size_t wmat = (size_t)ND * ND;
  __hip_bfloat16* xb    = (__hip_bfloat16*)d_ws;
  __hip_bfloat16* WtAll = xb + mat;
  __hip_bfloat16* Qw    = WtAll + 4 * wmat;
  __hip_bfloat16* Kw    = Qw + mat;
  __hip_bfloat16* Vtw   = Kw + mat;
  __hip_bfloat16* Cw    = Vtw + mat;
  float* mpg            = (float*)(Cw + mat);   // 8192 floats
  unsigned* mbits       = (unsigned*)(mpg + NM);  // 4 uints

  convert_bf16_kernel<<<(NM * ND / 8 + 255) / 256, 256, 0, stream>>>(
      x, xb, NM * ND / 8);
  hipMemsetAsync(mbits, 0, NB * sizeof(unsigned), stream);
  mask_perm_kernel<<<NM / 256, 256, 0, stream>>>(mask, mpg, mbits);
  transpose_w_kernel<<<dim3(ND / 64, ND / 64, 4), 256, 0, stream>>>(
      wq, wk, wv, wo, WtAll);

  qkv_gemm_kernel<<<dim3(3 * ND / 128, NM / 128), 256, 0, stream>>>(
      xb, WtAll, bq, bk, bv, Qw, Kw, Vtw);

  mha_mfma32_kernel<<<dim3(NS / 128, NH, NB), 128, 0, stream>>>(
      Qw, Kw, Vtw, mpg, mbits, Cw);

  gemm_bt_mfma_kernel<<<dim3(ND / 64, NM / 128), 256, 0, stream>>>(
      Cw, WtAll + 3 * wmat, bo, out, NM, ND, ND);
}

// Round 13
// 187.738 us; speedup vs baseline: 1.1179x; 1.1179x over previous
//
#include <hip/hip_runtime.h>
#include <hip/hip_bf16.h>

#define NB 4
#define NS 2048
#define ND 768
#define NH 12
#define NDH 64
#define NM (NB * NS)  // 8192

// fold 1/sqrt(64) * log2(e) into Q so softmax = exp2(s); mask pre-scaled
#define QSCALE 0.1803368867f
#define MSCALE (-1.442695041e9f)

typedef __attribute__((ext_vector_type(8))) short short8;    // 8 x bf16
typedef __attribute__((ext_vector_type(4))) float f32x4;
typedef __attribute__((ext_vector_type(16))) float f32x16;

__device__ __forceinline__ void async_ld16(const void* g, void* l) {
  __builtin_amdgcn_global_load_lds(
      (const __attribute__((address_space(1))) void*)g,
      (__attribute__((address_space(3))) void*)l, 16, 0, 0);
}

// plain scalar packing — compiler pairs these into v_cvt_pk_bf16_f32
__device__ __forceinline__ unsigned pack_bf16(float a, float b) {
  return ((unsigned)__bfloat16_as_ushort(__float2bfloat16(b)) << 16) |
         (unsigned)__bfloat16_as_ushort(__float2bfloat16(a));
}

// VALU cross-half exchange
__device__ __forceinline__ void permlane_swap(unsigned& a, unsigned& b) {
  asm("v_permlane32_swap_b32 %0, %1" : "+v"(a), "+v"(b));
}

// raw v_exp_f32: exp2 with flush-to-zero for large-negative (exact for mask)
__device__ __forceinline__ float fast_exp2(float x) {
  float r;
  asm("v_exp_f32 %0, %1" : "=v"(r) : "v"(x));
  return r;
}

// ---------------- f32 -> bf16 convert (vectorized, 8/thread) --------------
__global__ __launch_bounds__(256) void convert_bf16_kernel(
    const float* __restrict__ in, __hip_bfloat16* __restrict__ out, int n8) {
  const int i = blockIdx.x * 256 + threadIdx.x;
  if (i >= n8) return;
  const float4 a = ((const float4*)in)[i * 2];
  const float4 b = ((const float4*)in)[i * 2 + 1];
  short8 v;
  __hip_bfloat16* p = (__hip_bfloat16*)&v;
  p[0] = __float2bfloat16(a.x); p[1] = __float2bfloat16(a.y);
  p[2] = __float2bfloat16(a.z); p[3] = __float2bfloat16(a.w);
  p[4] = __float2bfloat16(b.x); p[5] = __float2bfloat16(b.y);
  p[6] = __float2bfloat16(b.z); p[7] = __float2bfloat16(b.w);
  ((short8*)out)[i] = v;
}

// ------- mask precompute: 32-key-round crow-permuted + per-(b,tile) bitmap -
// slot layout per 32-key round: slot = hi*16 + r <-> key = 4*hi+(r&3)+8*(r>>2)
__global__ __launch_bounds__(256) void mask_perm_kernel(
    const float* __restrict__ mask, float* __restrict__ mperm_g,
    unsigned* __restrict__ mbits) {
  const int idx = blockIdx.x * 256 + threadIdx.x;  // 0..8191
  const int b = idx >> 11;
  const int sb = idx & 2047;
  const int round = sb >> 5, slot = sb & 31;
  const int hh = slot >> 4, r = slot & 15;
  const int key = round * 32 + 4 * hh + (r & 3) + 8 * (r >> 2);
  const float v = mask[b * NS + key];
  mperm_g[idx] = v * MSCALE;
  if (v != 0.f) atomicOr(&mbits[b], 1u << (key >> 6));
}

// ------- weight transpose+convert: W[K][N] f32 -> Wt[N][K] bf16 -----------
__global__ __launch_bounds__(256) void transpose_w_kernel(
    const float* __restrict__ w0, const float* __restrict__ w1,
    const float* __restrict__ w2, const float* __restrict__ w3,
    __hip_bfloat16* __restrict__ WtAll) {
  __shared__ __hip_bfloat16 tile[64][66];
  const float* src = blockIdx.z == 0 ? w0 : blockIdx.z == 1 ? w1
                   : blockIdx.z == 2 ? w2 : w3;
  __hip_bfloat16* dst = WtAll + (size_t)blockIdx.z * ND * ND;
  const int kk0 = blockIdx.y * 64, nn0 = blockIdx.x * 64;
  const int t = threadIdx.x;
#pragma unroll
  for (int p = 0; p < 4; ++p) {
    const int idx = p * 256 + t;
    const int k = idx >> 4;
    const int c = (idx & 15) * 4;
    const float4 v = *(const float4*)(src + (size_t)(kk0 + k) * ND + nn0 + c);
    __hip_bfloat162* tp = (__hip_bfloat162*)&tile[k][c];
    tp[0] = __hip_bfloat162{__float2bfloat16(v.x), __float2bfloat16(v.y)};
    tp[1] = __hip_bfloat162{__float2bfloat16(v.z), __float2bfloat16(v.w)};
  }
  __syncthreads();
#pragma unroll
  for (int p = 0; p < 2; ++p) {
    const int idx = p * 256 + t;
    const int n = idx >> 3;
    const int kb = (idx & 7) * 8;
    short8 v;
    __hip_bfloat16* pv = (__hip_bfloat16*)&v;
#pragma unroll
    for (int j = 0; j < 8; ++j) pv[j] = tile[kb + j][n];
    *(short8*)(dst + (size_t)(nn0 + n) * ND + kk0 + kb) = v;
  }
}

// ------- fused QKV GEMM: 128x128 tile, BK=32, XCD-grouped blocks ----------
__global__ __launch_bounds__(256) void qkv_gemm_kernel(
    const __hip_bfloat16* __restrict__ A,
    const __hip_bfloat16* __restrict__ Bt,
    const float* __restrict__ bq, const float* __restrict__ bk,
    const float* __restrict__ bv,
    __hip_bfloat16* __restrict__ Qw, __hip_bfloat16* __restrict__ Kw,
    __hip_bfloat16* __restrict__ Vt) {
  __shared__ __hip_bfloat16 As[128 * 32];  // [row][k] 8KB
  __shared__ __hip_bfloat16 Bs[128 * 32];  // [col][k] 8KB
  const int K = ND;
  const int tid = threadIdx.x;
  const int w = tid >> 6, l = tid & 63;
  const int lk = l & 15, lt = l >> 4;
  // bijective XCD grouping: 1152 blocks = 8 * 144
  const int p = blockIdx.x + 18 * blockIdx.y;
  const int swzb = (p & 7) * 144 + (p >> 3);
  const int m0 = (swzb / 18) * 128, n0 = (swzb % 18) * 128;
  const int wr = w >> 1, wc = w & 1;

  f32x4 acc[4][4] = {};

  const int arow = w * 32 + (l >> 2);   // +16 for second load
  const int acol = (l & 3) * 8;
  const __hip_bfloat16* aptr = A + (size_t)(m0 + arow) * K + acol;
  const __hip_bfloat16* bptr = Bt + (size_t)(n0 + arow) * K + acol;
  __hip_bfloat16* asb = As + w * 1024;
  __hip_bfloat16* bsb = Bs + w * 1024;

  for (int k0 = 0; k0 < K; k0 += 32) {
    __syncthreads();
    async_ld16(aptr + k0, asb);
    async_ld16(aptr + (size_t)16 * K + k0, asb + 512);
    async_ld16(bptr + k0, bsb);
    async_ld16(bptr + (size_t)16 * K + k0, bsb + 512);
    __syncthreads();

    short8 af[4], bf[4];
#pragma unroll
    for (int m = 0; m < 4; ++m)
      af[m] = *(const short8*)(As + (wr * 64 + m * 16 + lk) * 32 + lt * 8);
#pragma unroll
    for (int n = 0; n < 4; ++n)
      bf[n] = *(const short8*)(Bs + (wc * 64 + n * 16 + lk) * 32 + lt * 8);
#pragma unroll
    for (int m = 0; m < 4; ++m)
#pragma unroll
      for (int n = 0; n < 4; ++n)
        acc[m][n] =
            __builtin_amdgcn_mfma_f32_16x16x32_bf16(af[m], bf[n], acc[m][n], 0, 0, 0);
  }

  const int mi = n0 / ND;          // 0=Q, 1=K, 2=V (768/128=6: no straddle)
  const int nbase = n0 - mi * ND;
  const float* bp = mi == 0 ? bq : mi == 1 ? bk : bv;
  const float oscale = (mi == 0) ? QSCALE : 1.f;

#pragma unroll
  for (int n = 0; n < 4; ++n) {
    const int col = nbase + wc * 64 + n * 16 + lk;
    const float bb = bp[col];
#pragma unroll
    for (int m = 0; m < 4; ++m) {
      const int row = m0 + wr * 64 + m * 16 + lt * 4;
#pragma unroll
      for (int r = 0; r < 4; ++r) {
        const float v = (acc[m][n][r] + bb) * oscale;
        if (mi < 2) {
          (mi ? Kw : Qw)[(size_t)(row + r) * ND + col] = __float2bfloat16(v);
        } else {
          const int mrow = row + r;
          const int bidx = mrow >> 11, s = mrow & 2047;
          const int hh = col >> 6, dh = col & 63;
          Vt[(((size_t)bidx * NH + hh) * NDH + dh) * NS + s] = __float2bfloat16(v);
        }
      }
    }
  }
}

// ---------------- MFMA-32x32 flash attention, wave key-split --------------
// 4 waves = (q-group 0/1) x (key-half 0/1); each wave: 32 q x 1024 keys in
// 32-key rounds. No running max -> partials combine linearly at the end via
// LDS. Grid 1536 blocks, LDS 32KB, VGPR <128 -> ~20 waves/CU (vs 12).
__global__ __launch_bounds__(256) void mha_mfma32_kernel(
    const __hip_bfloat16* __restrict__ Qb, const __hip_bfloat16* __restrict__ Kb,
    const __hip_bfloat16* __restrict__ Vt, const float* __restrict__ mperm_g,
    const unsigned* __restrict__ maskbits, __hip_bfloat16* __restrict__ ctx) {
  // staging: [0,16384) K = [buf][kh][4KB]; [16384,32768) V likewise.
  // epilogue reuse: [0,16384) f32 partials, [16384,+256) l, then bounce.
  __shared__ __align__(16) char smem[32768];
  char* KsB = smem;
  char* VsB = smem + 16384;

  // bijective XCD swizzle: 1536 = 8*192; 6 (b,h) groups per XCD (3MB L2 set)
  const int p = blockIdx.x + 32 * (blockIdx.y + 12 * blockIdx.z);
  const int logical = (p & 7) * 192 + (p >> 3);
  const int qt = logical & 31;         // q-tile of 64
  const int rest = logical >> 5;       // 0..47
  const int h = rest % 12;
  const int b = rest / 12;

  const int tid = threadIdx.x;
  const int w = tid >> 6, l = tid & 63;
  const int l31 = l & 31, hi = l >> 5;
  const int qg = w & 1, kh = w >> 1;
  const int q0 = qt * 64 + qg * 32;
  const int khbase = kh * 1024;
  const unsigned mbitsb = maskbits[b];

  const __hip_bfloat16* qp = Qb + ((size_t)b * NS + q0 + l31) * ND + h * NDH;
  short8 qf[4];
#pragma unroll
  for (int ks = 0; ks < 4; ++ks)
    qf[ks] = *(const short8*)(qp + ks * 16 + hi * 8);

  f32x16 c0 = {}, c1 = {};
  const f32x16 z16 = {};
  float lpart = 0.f;

  // ---- staging addresses (pre-swizzled global source, linear LDS) ----
  // K half-tile: 32 rows x 128B; wave stages rows qg*16 + i*8 + (l>>3)
  const int krow0 = qg * 16 + (l >> 3);
  const int krow1 = krow0 + 8;
  const __hip_bfloat16* kg0 = Kb + ((size_t)b * NS + khbase + krow0) * ND +
                              h * NDH + (((l & 7) ^ (krow0 & 7)) * 8);
  const __hip_bfloat16* kg1 = Kb + ((size_t)b * NS + khbase + krow1) * ND +
                              h * NDH + (((l & 7) ^ (krow1 & 7)) * 8);
  // V half-tile: 64 dh rows x 64B; wave stages rows qg*32 + i*16 + (l>>2)
  const int vrow0 = qg * 32 + (l >> 2);
  const int vrow1 = vrow0 + 16;
  const __hip_bfloat16* vg0 = Vt + (((size_t)b * NH + h) * NDH + vrow0) * NS +
                              khbase + (((l & 3) ^ ((vrow0 >> 1) & 3)) * 8);
  const __hip_bfloat16* vg1 = Vt + (((size_t)b * NH + h) * NDH + vrow1) * NS +
                              khbase + (((l & 3) ^ ((vrow1 >> 1) & 3)) * 8);
  const int sbase = kh * 4096 + qg * 2048;
  const float* mg = mperm_g + (size_t)b * NS;

  // uniform 4 async loads per wave per stage
#define STAGE(buf, r)                                                        \
  {                                                                          \
    char* kd = KsB + (buf) * 8192 + sbase;                                   \
    char* vd = VsB + (buf) * 8192 + sbase;                                   \
    const size_t koff = (size_t)(r) * 32 * ND;                               \
    async_ld16(kg0 + koff, kd);                                              \
    async_ld16(kg1 + koff, kd + 1024);                                       \
    async_ld16(vg0 + (r) * 32, vd);                                          \
    async_ld16(vg1 + (r) * 32, vd + 1024);                                   \
  }

  const int kswz = l31 & 7;          // K read-swizzle key
  const int vswz = (l31 >> 1) & 3;   // V read-swizzle key

  auto compute_round = [&](int r, int buf) {
    const int base = buf * 8192 + kh * 4096;
    // ---- QK^T over 32 keys (K rows l31), C from zero regs ----
    f32x16 s;
#pragma unroll
    for (int ks = 0; ks < 4; ++ks) {
      const int sIdx = (ks << 1) | hi;
      const short8 kf = *(const short8*)(KsB + base + (l31 << 7) +
                                         ((sIdx ^ kswz) << 4));
      s = __builtin_amdgcn_mfma_f32_32x32x16_bf16(kf, qf[ks],
                                                  ks == 0 ? z16 : s, 0, 0, 0);
    }

    // ---- rare mask path (bitmap per 64-key tile) ----
    if ((mbitsb >> (kh * 16 + (r >> 1))) & 1) {
      const float* mgt = mg + khbase + r * 32 + hi * 16;
#pragma unroll
      for (int rr = 0; rr < 16; ++rr) s[rr] += mgt[rr];
    }

    // ---- softmax terms ----
#pragma unroll
    for (int rr = 0; rr < 16; ++rr) {
      const float pv = fast_exp2(s[rr]);
      s[rr] = pv;
      lpart += pv;
    }

    // ---- PV: 2 key-slices; P^T frags via pack + permlane32_swap ----
#pragma unroll
    for (int ks2 = 0; ks2 < 2; ++ks2) {
      const int r0 = ks2 * 8;
      unsigned u0 = pack_bf16(s[r0 + 0], s[r0 + 1]);
      unsigned u1 = pack_bf16(s[r0 + 2], s[r0 + 3]);
      unsigned u2 = pack_bf16(s[r0 + 4], s[r0 + 5]);
      unsigned u3 = pack_bf16(s[r0 + 6], s[r0 + 7]);
      permlane_swap(u0, u2);
      permlane_swap(u1, u3);
      union { unsigned u[4]; short8 v; } pf = {{u0, u1, u2, u3}};
      const int sIdx2 = (ks2 << 1) | hi;
      const int voff = (sIdx2 ^ vswz) << 4;
      const short8 vf0 = *(const short8*)(VsB + base + (l31 << 6) + voff);
      const short8 vf1 = *(const short8*)(VsB + base + ((32 + l31) << 6) + voff);
      c0 = __builtin_amdgcn_mfma_f32_32x32x16_bf16(vf0, pf.v, c0, 0, 0, 0);
      c1 = __builtin_amdgcn_mfma_f32_32x32x16_bf16(vf1, pf.v, c1, 0, 0, 0);
    }
  };

  STAGE(0, 0);
  for (int r = 0; r < 32; ++r) {
    // round r's loads done; all waves synced -> buf (r+1)&1 free to restage
    asm volatile("s_waitcnt vmcnt(0) lgkmcnt(0)" ::: "memory");
    __builtin_amdgcn_s_barrier();
    if (r + 1 < 32) STAGE((r + 1) & 1, r + 1);
    compute_round(r, r & 1);
  }

  // ---- combine key-half partials ----
  lpart += __shfl_xor(lpart, 32);  // both hi halves -> lane holds l(q=l31, kh)
  asm volatile("s_waitcnt vmcnt(0) lgkmcnt(0)" ::: "memory");
  __syncthreads();

  float* numL = (float*)smem;                       // [qg][64 dh][32 q]
  float* lL = (float*)(smem + 16384);               // [qg][32]
  __hip_bfloat16* bounce = (__hip_bfloat16*)(smem + 16640);  // [64][76]

  if (kh == 1) {
#pragma unroll
    for (int mg2 = 0; mg2 < 2; ++mg2) {
      const f32x16& cc = mg2 ? c1 : c0;
#pragma unroll
      for (int rr = 0; rr < 16; ++rr) {
        const int dh = mg2 * 32 + 4 * hi + (rr & 3) + 8 * (rr >> 2);
        numL[qg * 2048 + dh * 32 + l31] = cc[rr];
      }
    }
    if (hi == 0) lL[qg * 32 + l31] = lpart;
  }
  __syncthreads();
  if (kh == 0) {
    const float inv = 1.f / (lpart + lL[qg * 32 + l31]);
#pragma unroll
    for (int mg2 = 0; mg2 < 2; ++mg2) {
      const f32x16& cc = mg2 ? c1 : c0;
#pragma unroll
      for (int rq = 0; rq < 4; ++rq) {
        const int dhb = mg2 * 32 + 4 * hi + 8 * rq;
        const float f0 = (cc[rq * 4 + 0] + numL[qg * 2048 + (dhb + 0) * 32 + l31]) * inv;
        const float f1 = (cc[rq * 4 + 1] + numL[qg * 2048 + (dhb + 1) * 32 + l31]) * inv;
        const float f2 = (cc[rq * 4 + 2] + numL[qg * 2048 + (dhb + 2) * 32 + l31]) * inv;
        const float f3 = (cc[rq * 4 + 3] + numL[qg * 2048 + (dhb + 3) * 32 + l31]) * inv;
        const unsigned u0 = pack_bf16(f0, f1);
        const unsigned u1 = pack_bf16(f2, f3);
        *(uint2*)(bounce + (qg * 32 + l31) * 76 + dhb) = uint2{u0, u1};
      }
    }
  }
  __syncthreads();
  // ---- coalesced stores: 64 q rows x 128B, 256 threads, 2 iters ----
#pragma unroll
  for (int it = 0; it < 2; ++it) {
    const int row = it * 32 + (tid >> 3);
    const __hip_bfloat16* src = bounce + row * 76 + (tid & 7) * 8;
    const uint2 a = *(const uint2*)(src);
    const uint2 b2 = *(const uint2*)(src + 4);
    __hip_bfloat16* gout =
        ctx + ((size_t)b * NS + qt * 64 + row) * ND + h * NDH + (tid & 7) * 8;
    *(uint4*)(gout) = uint4{a.x, a.y, b2.x, b2.y};
  }
#undef STAGE
}

// ---------------- MFMA GEMM (output proj): 128x64, f32 out ----------------
__global__ __launch_bounds__(256) void gemm_bt_mfma_kernel(
    const __hip_bfloat16* __restrict__ A, const __hip_bfloat16* __restrict__ Bt,
    const float* __restrict__ bias, float* __restrict__ Cout,
    int M, int N, int K) {
  __shared__ __hip_bfloat16 As[128 * 32];
  __shared__ __hip_bfloat16 Bs[64 * 32];
  const int tid = threadIdx.x;
  const int w = tid >> 6, l = tid & 63;
  const int lk = l & 15, lt = l >> 4;
  // bijective XCD grouping: 768 blocks = 8 * 96
  const int p = blockIdx.x + 12 * blockIdx.y;
  const int swzb = (p & 7) * 96 + (p >> 3);
  const int m0 = (swzb / 12) * 128, n0 = (swzb % 12) * 64;
  const int wr = w >> 1, wc = w & 1;

  f32x4 acc[4][2] = {};

  const int arow = w * 32 + (l >> 2);
  const int acol = (l & 3) * 8;
  const __hip_bfloat16* aptr = A + (size_t)(m0 + arow) * K + acol;
  const int brow = w * 16 + (l >> 2);
  const __hip_bfloat16* bptr = Bt + (size_t)(n0 + brow) * K + acol;
  __hip_bfloat16* asb = As + w * 1024;
  __hip_bfloat16* bsb = Bs + w * 512;

  for (int k0 = 0; k0 < K; k0 += 32) {
    __syncthreads();
    async_ld16(aptr + k0, asb);
    async_ld16(aptr + (size_t)16 * K + k0, asb + 512);
    async_ld16(bptr + k0, bsb);
    __syncthreads();

    short8 af[4], bf[2];
#pragma unroll
    for (int m = 0; m < 4; ++m)
      af[m] = *(const short8*)(As + (wr * 64 + m * 16 + lk) * 32 + lt * 8);
#pragma unroll
    for (int n = 0; n < 2; ++n)
      bf[n] = *(const short8*)(Bs + (wc * 32 + n * 16 + lk) * 32 + lt * 8);
#pragma unroll
    for (int m = 0; m < 4; ++m)
#pragma unroll
      for (int n = 0; n < 2; ++n)
        acc[m][n] =
            __builtin_amdgcn_mfma_f32_16x16x32_bf16(af[m], bf[n], acc[m][n], 0, 0, 0);
  }

#pragma unroll
  for (int n = 0; n < 2; ++n) {
    const int col = n0 + wc * 32 + n * 16 + lk;
    const float bb = bias[col];
#pragma unroll
    for (int m = 0; m < 4; ++m) {
      const int row = m0 + wr * 64 + m * 16 + lt * 4;
#pragma unroll
      for (int r = 0; r < 4; ++r)
        Cout[(size_t)(row + r) * N + col] = acc[m][n][r] + bb;
    }
  }
}

extern "C" void kernel_launch(void* const* d_in, const int* in_sizes, int n_in,
                              void* d_out, int out_size, void* d_ws, size_t ws_size,
                              hipStream_t stream) {
  const float* x    = (const float*)d_in[0];
  const float* mask = (const float*)d_in[1];
  const float* wq   = (const float*)d_in[2];
  const float* bq   = (const float*)d_in[3];
  const float* wk   = (const float*)d_in[4];
  const float* bk   = (const float*)d_in[5];
  const float* wv   = (const float*)d_in[6];
  const float* bv   = (const float*)d_in[7];
  const float* wo   = (const float*)d_in[8];
  const float* bo   = (const float*)d_in[9];
  float* out = (float*)d_out;

  const size_t mat = (size_t)NM * ND;
  const size_t wmat = (size_t)ND * ND;
  __hip_bfloat16* xb    = (__hip_bfloat16*)d_ws;
  __hip_bfloat16* WtAll = xb + mat;
  __hip_bfloat16* Qw    = WtAll + 4 * wmat;
  __hip_bfloat16* Kw    = Qw + mat;
  __hip_bfloat16* Vtw   = Kw + mat;
  __hip_bfloat16* Cw    = Vtw + mat;
  float* mpg            = (float*)(Cw + mat);   // 8192 floats
  unsigned* mbits       = (unsigned*)(mpg + NM);  // 4 uints

  convert_bf16_kernel<<<(NM * ND / 8 + 255) / 256, 256, 0, stream>>>(
      x, xb, NM * ND / 8);
  hipMemsetAsync(mbits, 0, NB * sizeof(unsigned), stream);
  mask_perm_kernel<<<NM / 256, 256, 0, stream>>>(mask, mpg, mbits);
  transpose_w_kernel<<<dim3(ND / 64, ND / 64, 4), 256, 0, stream>>>(
      wq, wk, wv, wo, WtAll);

  qkv_gemm_kernel<<<dim3(3 * ND / 128, NM / 128), 256, 0, stream>>>(
      xb, WtAll, bq, bk, bv, Qw, Kw, Vtw);

  mha_mfma32_kernel<<<dim3(32, 12, 4), 256, 0, stream>>>(
      Qw, Kw, Vtw, mpg, mbits, Cw);

  gemm_bt_mfma_kernel<<<dim3(ND / 64, NM / 128), 256, 0, stream>>>(
      Cw, WtAll + 3 * wmat, bo, out, NM, ND, ND);
}

// Round 14
// 171.164 us; speedup vs baseline: 1.2261x; 1.0968x over previous
//
#include <hip/hip_runtime.h>
#include <hip/hip_bf16.h>

#define NB 4
#define NS 2048
#define ND 768
#define NH 12
#define NDH 64
#define NM (NB * NS)  // 8192

// fold 1/sqrt(64) * log2(e) into Q so softmax = exp2(s); mask pre-scaled
#define QSCALE 0.1803368867f
#define MSCALE (-1.442695041e9f)

typedef __attribute__((ext_vector_type(8))) short short8;    // 8 x bf16
typedef __attribute__((ext_vector_type(4))) float f32x4;
typedef __attribute__((ext_vector_type(16))) float f32x16;

__device__ __forceinline__ void async_ld16(const void* g, void* l) {
  __builtin_amdgcn_global_load_lds(
      (const __attribute__((address_space(1))) void*)g,
      (__attribute__((address_space(3))) void*)l, 16, 0, 0);
}

// plain scalar packing — compiler pairs these into v_cvt_pk_bf16_f32
__device__ __forceinline__ unsigned pack_bf16(float a, float b) {
  return ((unsigned)__bfloat16_as_ushort(__float2bfloat16(b)) << 16) |
         (unsigned)__bfloat16_as_ushort(__float2bfloat16(a));
}

// VALU cross-half exchange
__device__ __forceinline__ void permlane_swap(unsigned& a, unsigned& b) {
  asm("v_permlane32_swap_b32 %0, %1" : "+v"(a), "+v"(b));
}

// raw v_exp_f32: exp2 with flush-to-zero for large-negative (exact for mask)
__device__ __forceinline__ float fast_exp2(float x) {
  float r;
  asm("v_exp_f32 %0, %1" : "=v"(r) : "v"(x));
  return r;
}

// ------- fused prep: x->bf16 | W^T bf16 | mask crow-perm + bitmap ---------
// blocks [0,3072): convert; [3072,3648): transpose_w; [3648,3652): mask.
__global__ __launch_bounds__(256) void prep_kernel(
    const float* __restrict__ x, const float* __restrict__ mask,
    const float* __restrict__ w0, const float* __restrict__ w1,
    const float* __restrict__ w2, const float* __restrict__ w3,
    __hip_bfloat16* __restrict__ xb, float* __restrict__ mperm_g,
    unsigned* __restrict__ mbits, __hip_bfloat16* __restrict__ WtAll) {
  __shared__ __align__(16) char pshm[8448];
  const int bid = blockIdx.x;
  const int t = threadIdx.x;

  if (bid < 3072) {
    // ---- convert: 8 f32 -> 8 bf16 per thread, exact coverage ----
    const int i = bid * 256 + t;
    const float4 a = ((const float4*)x)[i * 2];
    const float4 b = ((const float4*)x)[i * 2 + 1];
    short8 v;
    __hip_bfloat16* p = (__hip_bfloat16*)&v;
    p[0] = __float2bfloat16(a.x); p[1] = __float2bfloat16(a.y);
    p[2] = __float2bfloat16(a.z); p[3] = __float2bfloat16(a.w);
    p[4] = __float2bfloat16(b.x); p[5] = __float2bfloat16(b.y);
    p[6] = __float2bfloat16(b.z); p[7] = __float2bfloat16(b.w);
    ((short8*)xb)[i] = v;
  } else if (bid < 3648) {
    // ---- weight transpose: W[K][N] f32 -> Wt[N][K] bf16 ----
    auto tile = (__hip_bfloat16(*)[66])pshm;
    const int tt = bid - 3072;           // 0..575 = 4 * 12 * 12
    const int bz = tt / 144;
    const int rem = tt % 144;
    const int kk0 = (rem / 12) * 64, nn0 = (rem % 12) * 64;
    const float* src = bz == 0 ? w0 : bz == 1 ? w1 : bz == 2 ? w2 : w3;
    __hip_bfloat16* dst = WtAll + (size_t)bz * ND * ND;
#pragma unroll
    for (int pp = 0; pp < 4; ++pp) {
      const int idx = pp * 256 + t;
      const int k = idx >> 4;
      const int c = (idx & 15) * 4;
      const float4 v = *(const float4*)(src + (size_t)(kk0 + k) * ND + nn0 + c);
      __hip_bfloat162* tp = (__hip_bfloat162*)&tile[k][c];
      tp[0] = __hip_bfloat162{__float2bfloat16(v.x), __float2bfloat16(v.y)};
      tp[1] = __hip_bfloat162{__float2bfloat16(v.z), __float2bfloat16(v.w)};
    }
    __syncthreads();
#pragma unroll
    for (int pp = 0; pp < 2; ++pp) {
      const int idx = pp * 256 + t;
      const int n = idx >> 3;
      const int kb = (idx & 7) * 8;
      short8 v;
      __hip_bfloat16* pv = (__hip_bfloat16*)&v;
#pragma unroll
      for (int j = 0; j < 8; ++j) pv[j] = tile[kb + j][n];
      *(short8*)(dst + (size_t)(nn0 + n) * ND + kk0 + kb) = v;
    }
  } else {
    // ---- mask: crow-permuted + scaled, per-(b,tile) nonzero bitmap ----
    // slot = g*32 + hi*16 + r  <->  key = tile*64 + g*32 + 4*hi+(r&3)+8*(r>>2)
    unsigned* red = (unsigned*)pshm;
    const int b = bid - 3648;
    unsigned mymask = 0;
#pragma unroll
    for (int j = 0; j < 8; ++j) {
      const int sb = t * 8 + j;
      const int tile = sb >> 6, slot = sb & 63;
      const int g = slot >> 5, hh = (slot >> 4) & 1, r = slot & 15;
      const int key = tile * 64 + g * 32 + 4 * hh + (r & 3) + 8 * (r >> 2);
      const float v = mask[b * NS + key];
      mperm_g[b * 2048 + sb] = v * MSCALE;
      if (v != 0.f) mymask |= 1u << tile;
    }
    red[t] = mymask;
    __syncthreads();
    for (int s = 128; s > 0; s >>= 1) {
      if (t < s) red[t] |= red[t + s];
      __syncthreads();
    }
    if (t == 0) mbits[b] = red[0];
  }
}

// ------- fused QKV GEMM: 128x128 tile, BK=32, XCD-grouped blocks ----------
// LDS slot-swizzle key (row>>1)&3: frag reads 8-way -> 2-way (free).
__global__ __launch_bounds__(256) void qkv_gemm_kernel(
    const __hip_bfloat16* __restrict__ A,
    const __hip_bfloat16* __restrict__ Bt,
    const float* __restrict__ bq, const float* __restrict__ bk,
    const float* __restrict__ bv,
    __hip_bfloat16* __restrict__ Qw, __hip_bfloat16* __restrict__ Kw,
    __hip_bfloat16* __restrict__ Vt) {
  __shared__ __hip_bfloat16 As[128 * 32];  // [row][k] 8KB
  __shared__ __hip_bfloat16 Bs[128 * 32];  // [col][k] 8KB
  const int K = ND;
  const int tid = threadIdx.x;
  const int w = tid >> 6, l = tid & 63;
  const int lk = l & 15, lt = l >> 4;
  // bijective XCD grouping: 1152 blocks = 8 * 144
  const int p = blockIdx.x + 18 * blockIdx.y;
  const int swzb = (p & 7) * 144 + (p >> 3);
  const int m0 = (swzb / 18) * 128, n0 = (swzb % 18) * 128;
  const int wr = w >> 1, wc = w & 1;

  f32x4 acc[4][4] = {};

  const int arow = w * 32 + (l >> 2);   // +16 for second load
  const int acol = ((l & 3) ^ ((l >> 3) & 3)) * 8;   // pre-swizzled source
  const __hip_bfloat16* aptr = A + (size_t)(m0 + arow) * K + acol;
  const __hip_bfloat16* bptr = Bt + (size_t)(n0 + arow) * K + acol;
  __hip_bfloat16* asb = As + w * 1024;
  __hip_bfloat16* bsb = Bs + w * 1024;

  const int sslot = (lt ^ ((lk >> 1) & 3)) << 3;     // swizzled read slot

  for (int k0 = 0; k0 < K; k0 += 32) {
    __syncthreads();
    async_ld16(aptr + k0, asb);
    async_ld16(aptr + (size_t)16 * K + k0, asb + 512);
    async_ld16(bptr + k0, bsb);
    async_ld16(bptr + (size_t)16 * K + k0, bsb + 512);
    __syncthreads();

    short8 af[4], bf[4];
#pragma unroll
    for (int m = 0; m < 4; ++m)
      af[m] = *(const short8*)(As + (wr * 64 + m * 16 + lk) * 32 + sslot);
#pragma unroll
    for (int n = 0; n < 4; ++n)
      bf[n] = *(const short8*)(Bs + (wc * 64 + n * 16 + lk) * 32 + sslot);
#pragma unroll
    for (int m = 0; m < 4; ++m)
#pragma unroll
      for (int n = 0; n < 4; ++n)
        acc[m][n] =
            __builtin_amdgcn_mfma_f32_16x16x32_bf16(af[m], bf[n], acc[m][n], 0, 0, 0);
  }

  const int mi = n0 / ND;          // 0=Q, 1=K, 2=V (768/128=6: no straddle)
  const int nbase = n0 - mi * ND;
  const float* bp = mi == 0 ? bq : mi == 1 ? bk : bv;
  const float oscale = (mi == 0) ? QSCALE : 1.f;

#pragma unroll
  for (int n = 0; n < 4; ++n) {
    const int col = nbase + wc * 64 + n * 16 + lk;
    const float bb = bp[col];
#pragma unroll
    for (int m = 0; m < 4; ++m) {
      const int row = m0 + wr * 64 + m * 16 + lt * 4;
#pragma unroll
      for (int r = 0; r < 4; ++r) {
        const float v = (acc[m][n][r] + bb) * oscale;
        if (mi < 2) {
          (mi ? Kw : Qw)[(size_t)(row + r) * ND + col] = __float2bfloat16(v);
        } else {
          const int mrow = row + r;
          const int bidx = mrow >> 11, s = mrow & 2047;
          const int hh = col >> 6, dh = col & 63;
          Vt[(((size_t)bidx * NH + hh) * NDH + dh) * NS + s] = __float2bfloat16(v);
        }
      }
    }
  }
}

// ---------------- MFMA-32x32 flash attention (R10 structure) --------------
// XCD-swizzled blocks (K/V L2-resident per XCD), double-buffered LDS
// staging, vmcnt(0)+barrier per tile. Softmax denominator accumulated via
// MFMA with an all-ones A-fragment (lacc) — no VALU adds, no final shfl.
__global__ __launch_bounds__(256) void mha_mfma32_kernel(
    const __hip_bfloat16* __restrict__ Qb, const __hip_bfloat16* __restrict__ Kb,
    const __hip_bfloat16* __restrict__ Vt, const float* __restrict__ mperm_g,
    const unsigned* __restrict__ maskbits, __hip_bfloat16* __restrict__ ctx) {
  // [0,16384): K bufs (2x8KB) | [16384,32768): V bufs
  __shared__ __align__(16) char smem[32768];
  char* KsB = smem;
  char* VsB = smem + 16384;

  // bijective XCD swizzle: physical p -> logical (p&7)*96 + (p>>3)
  const int p = blockIdx.x + 16 * (blockIdx.y + 12 * blockIdx.z);
  const int logical = (p & 7) * 96 + (p >> 3);
  const int lx = logical & 15;         // q-tile
  const int rest = logical >> 4;       // 0..47
  const int h = rest % 12;
  const int b = rest / 12;

  const int tid = threadIdx.x;
  const int w = tid >> 6, l = tid & 63;
  const int l31 = l & 31, hi = l >> 5;
  const int q0 = lx * 128 + w * 32;
  const unsigned mbitsb = maskbits[b];   // wave-uniform

  const __hip_bfloat16* qp = Qb + ((size_t)b * NS + q0 + l31) * ND + h * NDH;
  short8 qf[4];
#pragma unroll
  for (int ks = 0; ks < 4; ++ks)
    qf[ks] = *(const short8*)(qp + ks * 16 + hi * 8);

  // all-ones bf16 A-fragment for the denominator MFMA
  const short ONEB = 0x3F80;
  const short8 ones = {ONEB, ONEB, ONEB, ONEB, ONEB, ONEB, ONEB, ONEB};

  f32x16 c0 = {}, c1 = {}, lacc = {};
  const f32x16 z16 = {};

  const int srow = l >> 3, slot = l & 7;
  const int key1 = w * 8 + srow, key2 = key1 + 32;
  const __hip_bfloat16* kg1 =
      Kb + ((size_t)b * NS + key1) * ND + h * NDH + (slot ^ (key1 & 7)) * 8;
  const __hip_bfloat16* kg2 =
      Kb + ((size_t)b * NS + key2) * ND + h * NDH + (slot ^ (key2 & 7)) * 8;
  const __hip_bfloat16* vg1 =
      Vt + (((size_t)b * NH + h) * NDH + key1) * NS + (slot ^ (key1 & 7)) * 8;
  const __hip_bfloat16* vg2 =
      Vt + (((size_t)b * NH + h) * NDH + key2) * NS + (slot ^ (key2 & 7)) * 8;
  const int ldsoff = w * 1024;
  const float* mg = mperm_g + (size_t)b * NS;  // crow-permuted, pre-scaled

  // uniform 4 async loads per wave per stage (vmcnt accounting)
#define STAGE(buf, t)                                                        \
  {                                                                          \
    const size_t koff = (size_t)(t) * 64 * ND;                               \
    char* kd = KsB + (buf) * 8192 + ldsoff;                                  \
    char* vd = VsB + (buf) * 8192 + ldsoff;                                  \
    async_ld16(kg1 + koff, kd);                                              \
    async_ld16(kg2 + koff, kd + 4096);                                       \
    async_ld16(vg1 + (t) * 64, vd);                                          \
    async_ld16(vg2 + (t) * 64, vd + 4096);                                   \
  }

  const int swz = (l31 & 7) << 4;

  auto compute_tile = [&](int t, int cur2) {
    const int bufo = cur2 * 8192;
    // ---- QK^T, C starts from persistent zero regs ----
    f32x16 s0, s1;
#pragma unroll
    for (int ks = 0; ks < 4; ++ks) {
      const int off = (((ks << 5) | (hi << 4)) ^ swz);
      const short8 kf0 = *(const short8*)(KsB + bufo + (l31 << 7) + off);
      const short8 kf1 = *(const short8*)(KsB + bufo + ((32 + l31) << 7) + off);
      if (ks == 0) {
        s0 = __builtin_amdgcn_mfma_f32_32x32x16_bf16(kf0, qf[0], z16, 0, 0, 0);
        s1 = __builtin_amdgcn_mfma_f32_32x32x16_bf16(kf1, qf[0], z16, 0, 0, 0);
      } else {
        s0 = __builtin_amdgcn_mfma_f32_32x32x16_bf16(kf0, qf[ks], s0, 0, 0, 0);
        s1 = __builtin_amdgcn_mfma_f32_32x32x16_bf16(kf1, qf[ks], s1, 0, 0, 0);
      }
    }

    // ---- rare path: this tile has nonzero mask values (additive) ----
    if ((mbitsb >> t) & 1) {
      const float* mgt = mg + t * 64 + hi * 16;
#pragma unroll
      for (int r = 0; r < 16; ++r) {
        s0[r] += mgt[r];
        s1[r] += mgt[32 + r];
      }
    }

    // ---- softmax: p = exp2(s), raw v_exp_f32 (sum deferred to MFMA) ----
#pragma unroll
    for (int r = 0; r < 16; ++r) s0[r] = fast_exp2(s0[r]);
#pragma unroll
    for (int r = 0; r < 16; ++r) s1[r] = fast_exp2(s1[r]);

    // ---- PV: P^T B-frags via pack + permlane32_swap; lacc via ones-MFMA --
#pragma unroll
    for (int ks = 0; ks < 4; ++ks) {
      const f32x16& S = (ks < 2) ? s0 : s1;
      const int r0 = (ks & 1) * 8;
      unsigned u0 = pack_bf16(S[r0 + 0], S[r0 + 1]);
      unsigned u1 = pack_bf16(S[r0 + 2], S[r0 + 3]);
      unsigned u2 = pack_bf16(S[r0 + 4], S[r0 + 5]);
      unsigned u3 = pack_bf16(S[r0 + 6], S[r0 + 7]);
      permlane_swap(u0, u2);
      permlane_swap(u1, u3);
      union { unsigned u[4]; short8 v; } pf = {{u0, u1, u2, u3}};
      const int off = (((ks << 5) | (hi << 4)) ^ swz);
      const short8 vf0 = *(const short8*)(VsB + bufo + (l31 << 7) + off);
      c0 = __builtin_amdgcn_mfma_f32_32x32x16_bf16(vf0, pf.v, c0, 0, 0, 0);
      const short8 vf1 = *(const short8*)(VsB + bufo + ((32 + l31) << 7) + off);
      c1 = __builtin_amdgcn_mfma_f32_32x32x16_bf16(vf1, pf.v, c1, 0, 0, 0);
      lacc = __builtin_amdgcn_mfma_f32_32x32x16_bf16(ones, pf.v, lacc, 0, 0, 0);
    }
  };

  STAGE(0, 0);
  for (int t = 0; t < 32; ++t) {
    // tile t's 4 loads done; all waves synced -> buf (t+1)&1 free to restage
    asm volatile("s_waitcnt vmcnt(0) lgkmcnt(0)" ::: "memory");
    __builtin_amdgcn_s_barrier();
    if (t + 1 < 32) STAGE((t + 1) & 1, t + 1);
    compute_tile(t, t & 1);
  }

  // every row of lacc holds this lane's q-row denominator
  const float inv = 1.f / lacc[0];

  // ---- epilogue: LDS bounce [32][76] -> 16B stores ----
  __syncthreads();
  __hip_bfloat16* cb = (__hip_bfloat16*)(smem + w * 4864);  // 32*76*2 B
#pragma unroll
  for (int mg2 = 0; mg2 < 2; ++mg2) {
    const f32x16& cc = mg2 ? c1 : c0;
#pragma unroll
    for (int rr = 0; rr < 4; ++rr) {
      const unsigned u0 = pack_bf16(cc[rr * 4 + 0] * inv, cc[rr * 4 + 1] * inv);
      const unsigned u1 = pack_bf16(cc[rr * 4 + 2] * inv, cc[rr * 4 + 3] * inv);
      *(uint2*)(cb + l31 * 76 + mg2 * 32 + 4 * hi + 8 * rr) = uint2{u0, u1};
    }
  }
  __syncthreads();
  const __hip_bfloat16* crd =
      (const __hip_bfloat16*)(smem + w * 4864) + (l >> 1) * 76 + (l & 1) * 8;
  __hip_bfloat16* gout =
      ctx + ((size_t)b * NS + q0 + (l >> 1)) * ND + h * NDH + (l & 1) * 8;
#pragma unroll
  for (int i = 0; i < 4; ++i) {
    const uint2 a = *(const uint2*)(crd + i * 16);
    const uint2 b2 = *(const uint2*)(crd + i * 16 + 4);
    *(uint4*)(gout + i * 16) = uint4{a.x, a.y, b2.x, b2.y};
  }
#undef STAGE
}

// ---------------- MFMA GEMM (output proj): 128x64, f32 out ----------------
// Same (row>>1)&3 LDS slot-swizzle as qkv_gemm.
__global__ __launch_bounds__(256) void gemm_bt_mfma_kernel(
    const __hip_bfloat16* __restrict__ A, const __hip_bfloat16* __restrict__ Bt,
    const float* __restrict__ bias, float* __restrict__ Cout,
    int M, int N, int K) {
  __shared__ __hip_bfloat16 As[128 * 32];
  __shared__ __hip_bfloat16 Bs[64 * 32];
  const int tid = threadIdx.x;
  const int w = tid >> 6, l = tid & 63;
  const int lk = l & 15, lt = l >> 4;
  // bijective XCD grouping: 768 blocks = 8 * 96
  const int p = blockIdx.x + 12 * blockIdx.y;
  const int swzb = (p & 7) * 96 + (p >> 3);
  const int m0 = (swzb / 12) * 128, n0 = (swzb % 12) * 64;
  const int wr = w >> 1, wc = w & 1;

  f32x4 acc[4][2] = {};

  const int arow = w * 32 + (l >> 2);
  const int acol = ((l & 3) ^ ((l >> 3) & 3)) * 8;   // pre-swizzled source
  const __hip_bfloat16* aptr = A + (size_t)(m0 + arow) * K + acol;
  const int brow = w * 16 + (l >> 2);
  const __hip_bfloat16* bptr = Bt + (size_t)(n0 + brow) * K + acol;
  __hip_bfloat16* asb = As + w * 1024;
  __hip_bfloat16* bsb = Bs + w * 512;

  const int sslot = (lt ^ ((lk >> 1) & 3)) << 3;     // swizzled read slot

  for (int k0 = 0; k0 < K; k0 += 32) {
    __syncthreads();
    async_ld16(aptr + k0, asb);
    async_ld16(aptr + (size_t)16 * K + k0, asb + 512);
    async_ld16(bptr + k0, bsb);
    __syncthreads();

    short8 af[4], bf[2];
#pragma unroll
    for (int m = 0; m < 4; ++m)
      af[m] = *(const short8*)(As + (wr * 64 + m * 16 + lk) * 32 + sslot);
#pragma unroll
    for (int n = 0; n < 2; ++n)
      bf[n] = *(const short8*)(Bs + (wc * 32 + n * 16 + lk) * 32 + sslot);
#pragma unroll
    for (int m = 0; m < 4; ++m)
#pragma unroll
      for (int n = 0; n < 2; ++n)
        acc[m][n] =
            __builtin_amdgcn_mfma_f32_16x16x32_bf16(af[m], bf[n], acc[m][n], 0, 0, 0);
  }

#pragma unroll
  for (int n = 0; n < 2; ++n) {
    const int col = n0 + wc * 32 + n * 16 + lk;
    const float bb = bias[col];
#pragma unroll
    for (int m = 0; m < 4; ++m) {
      const int row = m0 + wr * 64 + m * 16 + lt * 4;
#pragma unroll
      for (int r = 0; r < 4; ++r)
        Cout[(size_t)(row + r) * N + col] = acc[m][n][r] + bb;
    }
  }
}

extern "C" void kernel_launch(void* const* d_in, const int* in_sizes, int n_in,
                              void* d_out, int out_size, void* d_ws, size_t ws_size,
                              hipStream_t stream) {
  const float* x    = (const float*)d_in[0];
  const float* mask = (const float*)d_in[1];
  const float* wq   = (const float*)d_in[2];
  const float* bq   = (const float*)d_in[3];
  const float* wk   = (const float*)d_in[4];
  const float* bk   = (const float*)d_in[5];
  const float* wv   = (const float*)d_in[6];
  const float* bv   = (const float*)d_in[7];
  const float* wo   = (const float*)d_in[8];
  const float* bo   = (const float*)d_in[9];
  float* out = (float*)d_out;

  const size_t mat = (size_t)NM * ND;
  const size_t wmat = (size_t)ND * ND;
  __hip_bfloat16* xb    = (__hip_bfloat16*)d_ws;
  __hip_bfloat16* WtAll = xb + mat;
  __hip_bfloat16* Qw    = WtAll + 4 * wmat;
  __hip_bfloat16* Kw    = Qw + mat;
  __hip_bfloat16* Vtw   = Kw + mat;
  __hip_bfloat16* Cw    = Vtw + mat;
  float* mpg            = (float*)(Cw + mat);   // 8192 floats
  unsigned* mbits       = (unsigned*)(mpg + NM);  // 4 uints

  // fused prep: convert (3072) + transpose_w (576) + mask (4) = 3652 blocks
  prep_kernel<<<3652, 256, 0, stream>>>(x, mask, wq, wk, wv, wo,
                                        xb, mpg, mbits, WtAll);

  qkv_gemm_kernel<<<dim3(3 * ND / 128, NM / 128), 256, 0, stream>>>(
      xb, WtAll, bq, bk, bv, Qw, Kw, Vtw);

  mha_mfma32_kernel<<<dim3(NS / 128, NH, NB), 256, 0, stream>>>(
      Qw, Kw, Vtw, mpg, mbits, Cw);

  gemm_bt_mfma_kernel<<<dim3(ND / 64, NM / 128), 256, 0, stream>>>(
      Cw, WtAll + 3 * wmat, bo, out, NM, ND, ND);
}